// Round 3
// baseline (4049.467 us; speedup 1.0000x reference)
//
#include <hip/hip_runtime.h>
#include <hip/hip_bf16.h>
#include <math.h>

static constexpr int NL=4, DM=128, DI=256, DS=16, DTR=8, NC=256;
static constexpr int Bb=24, Lx=3072, T=1024;
static constexpr int ROWS = Bb*T; // 24576

// ---------------- initial strided conv: x(B,3072) -> h0 (B,1024,128), plus reversed copy
__global__ __launch_bounds__(256) void k_conv0(const float* __restrict__ x,
    const float* __restrict__ cw, const float* __restrict__ cb,
    float* __restrict__ h0f, float* __restrict__ h0b){
  int idx = blockIdx.x*256 + threadIdx.x;     // B*T*DM total
  int c = idx & (DM-1);
  int t = (idx >> 7) & (T-1);
  int b = idx >> 17;
  const float* xr = x + b*Lx;
  float acc = cb[c];
  int base = 3*t - 1;
#pragma unroll
  for (int k=0;k<3;k++){
    int j = base + k;
    float xv = (j>=0 && j<Lx) ? xr[j] : 0.f;
    acc = fmaf(xv, cw[c*3+k], acc);
  }
  h0f[(b*T + t)*DM + c] = acc;
  h0b[(b*T + (T-1-t))*DM + c] = acc;
}

// ---------------- residual add + LayerNorm over DM=128. 1 wave per row, block=256 (4 rows)
__global__ __launch_bounds__(256) void k_add_ln(const float* __restrict__ hin,
    float* __restrict__ res, const float* __restrict__ lnw, const float* __restrict__ lnb,
    float* __restrict__ hn, int first){
  int row = blockIdx.x*4 + (threadIdx.x >> 6);
  int lane = threadIdx.x & 63;
  const float* hr = hin + (long)row*DM;
  float* rr = res + (long)row*DM;
  float v0 = hr[lane], v1 = hr[lane+64];
  if (!first){ v0 += rr[lane]; v1 += rr[lane+64]; }
  rr[lane] = v0; rr[lane+64] = v1;
  float s = v0+v1;
#pragma unroll
  for (int m=1;m<64;m<<=1) s += __shfl_xor(s, m);
  float mu = s * (1.f/128.f);
  float d0 = v0-mu, d1 = v1-mu;
  float q = d0*d0 + d1*d1;
#pragma unroll
  for (int m=1;m<64;m<<=1) q += __shfl_xor(q, m);
  float rstd = rsqrtf(q*(1.f/128.f) + 1e-5f);
  hn[(long)row*DM+lane]    = d0*rstd*lnw[lane]    + lnb[lane];
  hn[(long)row*DM+lane+64] = d1*rstd*lnw[lane+64] + lnb[lane+64];
}

// ---------------- f32 GEMM: C[M][N] = A[M][K] * W[N][K]^T ; BM=BN=128, BK=16, 8x8 microtile
template<int N, int K>
__global__ __launch_bounds__(256) void k_gemm(const float* __restrict__ A,
    const float* __restrict__ W, float* __restrict__ C){
  __shared__ __align__(16) float As[16][132];
  __shared__ __align__(16) float Ws[16][132];
  int bm = blockIdx.x, bn = blockIdx.y;
  int tid = threadIdx.x;
  int tx = tid & 15, ty = tid >> 4;
  float acc[8][8] = {};
  const float* Ab = A + (long)bm*128*K;
  const float* Wb = W + (long)bn*128*K;
  for (int kb = 0; kb < K; kb += 16){
    for (int lin = tid; lin < 2048; lin += 256){
      int k = lin & 15, m = lin >> 4;
      As[k][m] = Ab[m*K + kb + k];
      Ws[k][m] = Wb[m*K + kb + k];
    }
    __syncthreads();
#pragma unroll
    for (int k=0;k<16;k++){
      float a[8], w[8];
      const float4* ar = reinterpret_cast<const float4*>(&As[k][0]);
      const float4* wr = reinterpret_cast<const float4*>(&Ws[k][0]);
      float4 a0 = ar[ty*2], a1 = ar[ty*2+1];
      float4 w0 = wr[tx*2], w1 = wr[tx*2+1];
      a[0]=a0.x;a[1]=a0.y;a[2]=a0.z;a[3]=a0.w;a[4]=a1.x;a[5]=a1.y;a[6]=a1.z;a[7]=a1.w;
      w[0]=w0.x;w[1]=w0.y;w[2]=w0.z;w[3]=w0.w;w[4]=w1.x;w[5]=w1.y;w[6]=w1.z;w[7]=w1.w;
#pragma unroll
      for (int i=0;i<8;i++)
#pragma unroll
        for (int j=0;j<8;j++) acc[i][j] = fmaf(a[i], w[j], acc[i][j]);
    }
    __syncthreads();
  }
  float* Cb = C + ((long)bm*128)*N + bn*128;
#pragma unroll
  for (int i=0;i<8;i++)
#pragma unroll
    for (int j=0;j<8;j++)
      Cb[(ty*8+i)*N + tx*8+j] = acc[i][j];
}

// ---------------- causal depthwise conv (k=4, pad 3 left) + SiLU ; x = xz[...,0:256]
__global__ __launch_bounds__(256) void k_convs(const float* __restrict__ xz,
    const float* __restrict__ cw, const float* __restrict__ cb, float* __restrict__ xc){
  int idx = blockIdx.x*256 + threadIdx.x;     // B*T*DI
  int d = idx & (DI-1);
  int t = (idx >> 8) & (T-1);
  int b = idx >> 18;
  const float* xrow = xz + (long)b*T*2*DI;
  float acc = cb[d];
#pragma unroll
  for (int k=0;k<4;k++){
    int tt = t + k - 3;
    float xv = (tt>=0) ? xrow[(long)tt*2*DI + d] : 0.f;
    acc = fmaf(xv, cw[d*4+k], acc);
  }
  float s = acc / (1.f + __expf(-acc));
  xc[(long)(b*T+t)*DI + d] = s;
}

// ---------------- dbl = xc @ xp^T (40 cols), dt = softplus(dbl[:,:8] @ dtw^T + dtb), BC out
__global__ __launch_bounds__(256) void k_dbldt(const float* __restrict__ xc,
    const float* __restrict__ xp, const float* __restrict__ dtw, const float* __restrict__ dtb,
    float* __restrict__ gdt, float* __restrict__ bcg){
  __shared__ float xp_s[40][257];
  __shared__ float xc_s[16][257];
  __shared__ float dtw_s[DI][9];
  __shared__ float dtb_s[DI];
  __shared__ float dbl_s[16][41];
  int tid = threadIdx.x;
  long row0 = (long)blockIdx.x * 16;
  for (int lin = tid; lin < 40*DI; lin += 256){
    int n = lin >> 8, k = lin & 255;
    xp_s[n][k] = xp[lin];
  }
  for (int lin = tid; lin < DI*DTR; lin += 256)
    dtw_s[lin>>3][lin&7] = dtw[lin];
  dtb_s[tid] = dtb[tid];
  for (int lin = tid; lin < 16*DI; lin += 256){
    int r = lin >> 8, k = lin & 255;
    xc_s[r][k] = xc[(row0 + r)*DI + k];
  }
  __syncthreads();
  for (int idx = tid; idx < 16*40; idx += 256){
    int r = idx / 40, n = idx % 40;
    float acc = 0.f;
#pragma unroll 4
    for (int k=0;k<DI;k++) acc = fmaf(xc_s[r][k], xp_s[n][k], acc);
    dbl_s[r][n] = acc;
  }
  __syncthreads();
  {
    int d = tid;
    float w[8];
#pragma unroll
    for (int j=0;j<8;j++) w[j] = dtw_s[d][j];
    float bias = dtb_s[d];
    for (int r=0;r<16;r++){
      float acc = bias;
#pragma unroll
      for (int j=0;j<8;j++) acc = fmaf(dbl_s[r][j], w[j], acc);
      float sp = (acc > 20.f) ? acc : log1pf(__expf(acc));
      gdt[(row0 + r)*DI + d] = sp;
    }
  }
  for (int idx = tid; idx < 16*32; idx += 256){
    int r = idx >> 5, j = idx & 31;
    bcg[(row0 + r)*32 + j] = dbl_s[r][8 + j];
  }
}

// ---------------- selective scan. block = 16 d-channels x 16 states; grid (DI/16, B)
__global__ __launch_bounds__(256) void k_scan(const float* __restrict__ gdt,
    const float* __restrict__ bcg, const float* __restrict__ xcg, const float* __restrict__ xzg,
    const float* __restrict__ Alog, const float* __restrict__ Dp, float* __restrict__ yout){
  int b = blockIdx.y;
  int d0 = blockIdx.x * 16;
  int tid = threadIdx.x;
  int s = tid & 15, dl = tid >> 4;
  int d = d0 + dl;
  float A = -__expf(Alog[d*DS + s]);   // A = -exp(Alog)
  float Dd = Dp[d];
  __shared__ float dt_s[64][16], x_s[64][16], z_s[64][16], b_s[64][16], c_s[64][16], y_s[64][16];
  float h = 0.f;
  const long rowbase = (long)b*T;
  for (int t0 = 0; t0 < T; t0 += 64){
    for (int lin = tid; lin < 64*16; lin += 256){
      int i = lin >> 4, dd = lin & 15;
      long r = rowbase + t0 + i;
      dt_s[i][dd] = gdt[r*DI + d0 + dd];
      x_s[i][dd]  = xcg[r*DI + d0 + dd];
      z_s[i][dd]  = xzg[r*2*DI + DI + d0 + dd];
      b_s[i][dd]  = bcg[r*32 + dd];
      c_s[i][dd]  = bcg[r*32 + 16 + dd];
    }
    __syncthreads();
    for (int i=0;i<64;i++){
      float dtv = dt_s[i][dl];
      float xv  = x_s[i][dl];
      float decay = __expf(dtv * A);
      h = fmaf(decay, h, dtv*xv*b_s[i][s]);
      float p = h * c_s[i][s];
      p += __shfl_xor(p,1); p += __shfl_xor(p,2);
      p += __shfl_xor(p,4); p += __shfl_xor(p,8);
      if (s == 0){
        float zv = z_s[i][dl];
        y_s[i][dl] = (p + Dd*xv) * (zv / (1.f + __expf(-zv)));
      }
    }
    __syncthreads();
    for (int lin = tid; lin < 64*16; lin += 256){
      int i = lin >> 4, dd = lin & 15;
      yout[(rowbase + t0 + i)*DI + d0 + dd] = y_s[i][dd];
    }
    __syncthreads();
  }
}

// ---------------- final-row LN (only t = T-1 needed) -> comb half
__global__ __launch_bounds__(64) void k_final(const float* __restrict__ hcur,
    const float* __restrict__ res, const float* __restrict__ nfw, const float* __restrict__ nfb,
    float* __restrict__ comb, int half){
  int b = blockIdx.x;
  int lane = threadIdx.x;
  const float* h = hcur + ((long)b*T + (T-1))*DM;
  const float* r = res  + ((long)b*T + (T-1))*DM;
  float v0 = h[lane]+r[lane], v1 = h[lane+64]+r[lane+64];
  float s = v0+v1;
#pragma unroll
  for (int m=1;m<64;m<<=1) s += __shfl_xor(s, m);
  float mu = s * (1.f/128.f);
  float d0 = v0-mu, d1 = v1-mu;
  float q = d0*d0 + d1*d1;
#pragma unroll
  for (int m=1;m<64;m<<=1) q += __shfl_xor(q, m);
  float rstd = rsqrtf(q*(1.f/128.f) + 1e-5f);
  comb[b*2*DM + half*DM + lane]    = d0*rstd*nfw[lane]    + nfb[lane];
  comb[b*2*DM + half*DM + lane+64] = d1*rstd*nfw[lane+64] + nfb[lane+64];
}

// ---------------- head: out(24,256) = comb(24,256) @ head_w^T + head_b
__global__ __launch_bounds__(256) void k_head(const float* __restrict__ comb,
    const float* __restrict__ hw, const float* __restrict__ hb, float* __restrict__ out){
  int b = blockIdx.x, n = threadIdx.x;
  const float* cr = comb + b*2*DM;
  float acc = hb[n];
#pragma unroll 4
  for (int k=0;k<2*DM;k++) acc = fmaf(cr[k], hw[n*2*DM + k], acc);
  out[b*NC + n] = acc;
}

extern "C" void kernel_launch(void* const* d_in, const int* in_sizes, int n_in,
                              void* d_out, int out_size, void* d_ws, size_t ws_size,
                              hipStream_t stream){
  auto F = [&](int i){ return (const float*)d_in[i]; };
  float* ws = (float*)d_ws;
  size_t o = 0;
  float* h0f = ws + o; o += (size_t)ROWS*DM;
  float* h0b = ws + o; o += (size_t)ROWS*DM;
  float* res = ws + o; o += (size_t)ROWS*DM;
  float* hcur= ws + o; o += (size_t)ROWS*DM;
  float* xz  = ws + o; o += (size_t)ROWS*2*DI;
  float* xc  = ws + o; o += (size_t)ROWS*DI;
  float* gdt = ws + o; o += (size_t)ROWS*DI;
  float* bcg = ws + o; o += (size_t)ROWS*2*DS;
  float* yout= ws + o; o += (size_t)ROWS*DI;
  float* hn  = yout;   // hn dead before scan writes yout -> safe alias
  float* comb= ws + o; o += (size_t)Bb*2*DM;

  k_conv0<<<ROWS*DM/256, 256, 0, stream>>>(F(0), F(1), F(2), h0f, h0b);

  for (int dir = 0; dir < 2; dir++){
    int p = dir ? 14 : 3;   // f_* at 3..13, b_* at 14..24
    const float* hin = dir ? h0b : h0f;
    for (int l = 0; l < NL; l++){
      const float* hsrc = (l==0) ? hin : hcur;
      k_add_ln<<<ROWS/4, 256, 0, stream>>>(hsrc, res,
          F(p+9)+(size_t)l*DM, F(p+10)+(size_t)l*DM, hn, (l==0)?1:0);
      k_gemm<2*DI, DM><<<dim3(ROWS/128, (2*DI)/128), 256, 0, stream>>>(
          hn, F(p+0)+(size_t)l*2*DI*DM, xz);
      k_convs<<<ROWS*DI/256, 256, 0, stream>>>(xz,
          F(p+1)+(size_t)l*DI*4, F(p+2)+(size_t)l*DI, xc);
      k_dbldt<<<ROWS/16, 256, 0, stream>>>(xc,
          F(p+3)+(size_t)l*(DTR+2*DS)*DI, F(p+4)+(size_t)l*DI*DTR,
          F(p+5)+(size_t)l*DI, gdt, bcg);
      k_scan<<<dim3(DI/16, Bb), 256, 0, stream>>>(gdt, bcg, xc, xz,
          F(p+6)+(size_t)l*DI*DS, F(p+7)+(size_t)l*DI, yout);
      k_gemm<DM, DI><<<dim3(ROWS/128, DM/128), 256, 0, stream>>>(
          yout, F(p+8)+(size_t)l*DM*DI, hcur);
    }
    k_final<<<Bb, 64, 0, stream>>>(hcur, res, F(25), F(26), comb, dir);
  }
  k_head<<<Bb, 256, 0, stream>>>(comb, F(27), F(28), (float*)d_out);
}

// Round 4
// 2457.963 us; speedup vs baseline: 1.6475x; 1.6475x over previous
//
#include <hip/hip_runtime.h>
#include <hip/hip_bf16.h>
#include <math.h>

static constexpr int NL=4, DM=128, DI=256, DS=16, DTR=8, NC=256;
static constexpr int Bb=24, Lx=3072, T=1024;
static constexpr int ROWS = Bb*T;       // 24576
static constexpr int NCH=8, TC=128;     // scan chunking

typedef __attribute__((ext_vector_type(4))) float f32x4;
typedef __attribute__((ext_vector_type(8))) short bf16x8;

// f32 -> bf16 (round-to-nearest-even), header-independent
static __device__ inline unsigned short f2bf(float f){
  unsigned int u = __float_as_uint(f);
  unsigned int r = (u + 0x7FFFu + ((u >> 16) & 1u)) >> 16;
  return (unsigned short)r;
}

// ---------------- initial strided conv: x(B,3072) -> h0 (B,1024,128), plus reversed copy
__global__ __launch_bounds__(256) void k_conv0(const float* __restrict__ x,
    const float* __restrict__ cw, const float* __restrict__ cb,
    float* __restrict__ h0f, float* __restrict__ h0b){
  int idx = blockIdx.x*256 + threadIdx.x;     // B*T*DM total
  int c = idx & (DM-1);
  int t = (idx >> 7) & (T-1);
  int b = idx >> 17;
  const float* xr = x + b*Lx;
  float acc = cb[c];
  int base = 3*t - 1;
#pragma unroll
  for (int k=0;k<3;k++){
    int j = base + k;
    float xv = (j>=0 && j<Lx) ? xr[j] : 0.f;
    acc = fmaf(xv, cw[c*3+k], acc);
  }
  h0f[(b*T + t)*DM + c] = acc;
  h0b[(b*T + (T-1-t))*DM + c] = acc;
}

// ---------------- generic f32 -> bf16 cast
__global__ __launch_bounds__(256) void k_cast(const float* __restrict__ src,
    unsigned short* __restrict__ dst, int n){
  int i = blockIdx.x*256 + threadIdx.x;
  if (i < n) dst[i] = f2bf(src[i]);
}

// ---------------- residual add + LayerNorm over DM=128 -> bf16 hn. 1 wave/row, 4 rows/block
__global__ __launch_bounds__(256) void k_add_ln(const float* __restrict__ hin,
    float* __restrict__ res, const float* __restrict__ lnw, const float* __restrict__ lnb,
    unsigned short* __restrict__ hn, int first){
  int row = blockIdx.x*4 + (threadIdx.x >> 6);
  int lane = threadIdx.x & 63;
  const float* hr = hin + (long)row*DM;
  float* rr = res + (long)row*DM;
  float v0 = hr[lane], v1 = hr[lane+64];
  if (!first){ v0 += rr[lane]; v1 += rr[lane+64]; }
  rr[lane] = v0; rr[lane+64] = v1;
  float s = v0+v1;
#pragma unroll
  for (int m=1;m<64;m<<=1) s += __shfl_xor(s, m);
  float mu = s * (1.f/128.f);
  float d0 = v0-mu, d1 = v1-mu;
  float q = d0*d0 + d1*d1;
#pragma unroll
  for (int m=1;m<64;m<<=1) q += __shfl_xor(q, m);
  float rstd = rsqrtf(q*(1.f/128.f) + 1e-5f);
  hn[(long)row*DM+lane]    = f2bf(d0*rstd*lnw[lane]    + lnb[lane]);
  hn[(long)row*DM+lane+64] = f2bf(d1*rstd*lnw[lane+64] + lnb[lane+64]);
}

// ---------------- bf16 MFMA GEMM: C[M][N](f32) = A[M][K](bf16) * W[N][K](bf16)^T
// tile 128x128, 4 waves (2x2), each wave 64x64 via 4x4 frags of 16x16x32
template<int N, int K>
__global__ __launch_bounds__(256) void k_mgemm(const unsigned short* __restrict__ A,
    const unsigned short* __restrict__ W, float* __restrict__ C){
  constexpr int BK = 32;
  __shared__ short As[128*BK];
  __shared__ short Ws[128*BK];
  int tid = threadIdx.x;
  int lane = tid & 63, wave = tid >> 6;
  int wr = (wave >> 1) * 64, wc = (wave & 1) * 64;
  long bm = blockIdx.x, bn = blockIdx.y;
  const short* Ag = (const short*)A + bm*128*K;
  const short* Wg = (const short*)W + bn*128*K;
  f32x4 acc[4][4] = {};
  int r = lane & 15, kg = (lane >> 4) * 8;
  for (int kb = 0; kb < K; kb += BK){
#pragma unroll
    for (int t = 0; t < 2; t++){
      int c = tid + t*256;            // 512 chunks of 16B per 8KB tile
      int row = c >> 2, kc = (c & 3) * 8;
      *(bf16x8*)&As[row*BK + kc] = *(const bf16x8*)&Ag[row*K + kb + kc];
      *(bf16x8*)&Ws[row*BK + kc] = *(const bf16x8*)&Wg[row*K + kb + kc];
    }
    __syncthreads();
    bf16x8 af[4], wf[4];
#pragma unroll
    for (int m=0;m<4;m++) af[m] = *(const bf16x8*)&As[(wr + m*16 + r)*BK + kg];
#pragma unroll
    for (int n=0;n<4;n++) wf[n] = *(const bf16x8*)&Ws[(wc + n*16 + r)*BK + kg];
#pragma unroll
    for (int m=0;m<4;m++)
#pragma unroll
      for (int n=0;n<4;n++)
        acc[m][n] = __builtin_amdgcn_mfma_f32_16x16x32_bf16(af[m], wf[n], acc[m][n], 0, 0, 0);
    __syncthreads();
  }
  float* Cb = C + (bm*128)*N + bn*128;
  int rq = (lane >> 4) * 4, cn = lane & 15;
#pragma unroll
  for (int m=0;m<4;m++)
#pragma unroll
    for (int n=0;n<4;n++)
#pragma unroll
      for (int q=0;q<4;q++)
        Cb[(wr + m*16 + rq + q)*N + wc + n*16 + cn] = acc[m][n][q];
}

// ---------------- causal depthwise conv (k=4, pad 3 left) + SiLU ; x = xz[...,0:256]
__global__ __launch_bounds__(256) void k_convs(const float* __restrict__ xz,
    const float* __restrict__ cw, const float* __restrict__ cb, float* __restrict__ xc){
  int idx = blockIdx.x*256 + threadIdx.x;     // B*T*DI
  int d = idx & (DI-1);
  int t = (idx >> 8) & (T-1);
  int b = idx >> 18;
  const float* xrow = xz + (long)b*T*2*DI;
  float acc = cb[d];
#pragma unroll
  for (int k=0;k<4;k++){
    int tt = t + k - 3;
    float xv = (tt>=0) ? xrow[(long)tt*2*DI + d] : 0.f;
    acc = fmaf(xv, cw[d*4+k], acc);
  }
  float s = acc / (1.f + __expf(-acc));
  xc[(long)(b*T+t)*DI + d] = s;
}

// ---------------- dbl = xc @ xp^T (40 cols), dt = softplus(dbl[:,:8] @ dtw^T + dtb), BC out
__global__ __launch_bounds__(256) void k_dbldt(const float* __restrict__ xc,
    const float* __restrict__ xp, const float* __restrict__ dtw, const float* __restrict__ dtb,
    float* __restrict__ gdt, float* __restrict__ bcg){
  __shared__ float xp_s[40][257];
  __shared__ float xc_s[16][257];
  __shared__ float dtw_s[DI][9];
  __shared__ float dtb_s[DI];
  __shared__ float dbl_s[16][41];
  int tid = threadIdx.x;
  long row0 = (long)blockIdx.x * 16;
  for (int lin = tid; lin < 40*DI; lin += 256){
    int n = lin >> 8, k = lin & 255;
    xp_s[n][k] = xp[lin];
  }
  for (int lin = tid; lin < DI*DTR; lin += 256)
    dtw_s[lin>>3][lin&7] = dtw[lin];
  dtb_s[tid] = dtb[tid];
  for (int lin = tid; lin < 16*DI; lin += 256){
    int r = lin >> 8, k = lin & 255;
    xc_s[r][k] = xc[(row0 + r)*DI + k];
  }
  __syncthreads();
  for (int idx = tid; idx < 16*40; idx += 256){
    int r = idx / 40, n = idx % 40;
    float acc = 0.f;
#pragma unroll 4
    for (int k=0;k<DI;k++) acc = fmaf(xc_s[r][k], xp_s[n][k], acc);
    dbl_s[r][n] = acc;
  }
  __syncthreads();
  {
    int d = tid;
    float w[8];
#pragma unroll
    for (int j=0;j<8;j++) w[j] = dtw_s[d][j];
    float bias = dtb_s[d];
    for (int r=0;r<16;r++){
      float acc = bias;
#pragma unroll
      for (int j=0;j<8;j++) acc = fmaf(dbl_s[r][j], w[j], acc);
      float sp = (acc > 20.f) ? acc : log1pf(__expf(acc));
      gdt[(row0 + r)*DI + d] = sp;
    }
  }
  for (int idx = tid; idx < 16*32; idx += 256){
    int r = idx >> 5, j = idx & 31;
    bcg[(row0 + r)*32 + j] = dbl_s[r][8 + j];
  }
}

// ---------------- scan pass 1: per-chunk decay product + local final state (h0=0)
// grid (DI/16, NCH, Bb); block 256 = 16 d x 16 s
__global__ __launch_bounds__(256) void k_scan1(const float* __restrict__ gdt,
    const float* __restrict__ bcg, const float* __restrict__ xc,
    const float* __restrict__ Alog, float* __restrict__ Pd, float* __restrict__ Hl){
  int b = blockIdx.z, ch = blockIdx.y, d0 = blockIdx.x*16;
  int tid = threadIdx.x, s = tid & 15, dl = tid >> 4, d = d0 + dl;
  float A = -__expf(Alog[d*DS + s]);
  __shared__ float dt_s[TC][16], x_s[TC][16], b_s[TC][16];
  long r0 = (long)b*T + ch*TC;
  for (int lin = tid; lin < TC*4; lin += 256){
    int i = lin >> 2, c4 = (lin & 3)*4;
    *(float4*)&dt_s[i][c4] = *(const float4*)&gdt[(r0+i)*DI + d0 + c4];
    *(float4*)&x_s[i][c4]  = *(const float4*)&xc [(r0+i)*DI + d0 + c4];
    *(float4*)&b_s[i][c4]  = *(const float4*)&bcg[(r0+i)*32 + c4];
  }
  __syncthreads();
  float h = 0.f, lp = 0.f;
  for (int i0 = 0; i0 < TC; i0 += 8){
    float dtv[8], xv[8], bv[8];
#pragma unroll
    for (int j=0;j<8;j++){ dtv[j]=dt_s[i0+j][dl]; xv[j]=x_s[i0+j][dl]; bv[j]=b_s[i0+j][s]; }
#pragma unroll
    for (int j=0;j<8;j++){
      float da = dtv[j]*A;
      lp += da;
      h = fmaf(__expf(da), h, dtv[j]*xv[j]*bv[j]);
    }
  }
  long o = ((long)(b*NCH + ch)*DI + d)*DS + s;
  Pd[o] = __expf(lp);
  Hl[o] = h;
}

// ---------------- scan pass 2: sequential chunk combine -> per-chunk start states
__global__ __launch_bounds__(256) void k_scan2(const float* __restrict__ Pd,
    const float* __restrict__ Hl, float* __restrict__ Hst){
  int idx = blockIdx.x*256 + threadIdx.x;   // b*4096 + (d*16+s)
  int b = idx >> 12, j = idx & 4095;
  long base = (long)b*NCH*4096 + j;
  float h = 0.f;
#pragma unroll
  for (int c=0;c<NCH;c++){
    Hst[base + c*4096] = h;
    h = Pd[base + c*4096]*h + Hl[base + c*4096];
  }
}

// ---------------- scan pass 3: full local scan with correct h0, emit gated y (bf16)
// grid (DI/16, NCH, Bb); block 256 = 16 d x 16 s
__global__ __launch_bounds__(256) void k_scan3(const float* __restrict__ gdt,
    const float* __restrict__ bcg, const float* __restrict__ xc, const float* __restrict__ xz,
    const float* __restrict__ Alog, const float* __restrict__ Dp,
    const float* __restrict__ Hst, unsigned short* __restrict__ yg){
  int b = blockIdx.z, ch = blockIdx.y, d0 = blockIdx.x*16;
  int tid = threadIdx.x, s = tid & 15, dl = tid >> 4, d = d0 + dl;
  float A = -__expf(Alog[d*DS + s]);
  float Dd = Dp[d];
  __shared__ float dt_s[TC][16], x_s[TC][16], z_s[TC][16], b_s[TC][16], c_s[TC][16];
  __shared__ float y_s[TC][16];
  long r0 = (long)b*T + ch*TC;
  for (int lin = tid; lin < TC*4; lin += 256){
    int i = lin >> 2, c4 = (lin & 3)*4;
    *(float4*)&dt_s[i][c4] = *(const float4*)&gdt[(r0+i)*DI + d0 + c4];
    *(float4*)&x_s[i][c4]  = *(const float4*)&xc [(r0+i)*DI + d0 + c4];
    *(float4*)&z_s[i][c4]  = *(const float4*)&xz [(r0+i)*2*DI + DI + d0 + c4];
    *(float4*)&b_s[i][c4]  = *(const float4*)&bcg[(r0+i)*32 + c4];
    *(float4*)&c_s[i][c4]  = *(const float4*)&bcg[(r0+i)*32 + 16 + c4];
  }
  float h = Hst[((long)(b*NCH + ch)*DI + d)*DS + s];
  __syncthreads();
  for (int i0 = 0; i0 < TC; i0 += 8){
    float dtv[8], xv[8], bv[8], cv[8];
#pragma unroll
    for (int j=0;j<8;j++){
      dtv[j]=dt_s[i0+j][dl]; xv[j]=x_s[i0+j][dl];
      bv[j]=b_s[i0+j][s];    cv[j]=c_s[i0+j][s];
    }
#pragma unroll
    for (int j=0;j<8;j++){
      h = fmaf(__expf(dtv[j]*A), h, dtv[j]*xv[j]*bv[j]);
      float p = h * cv[j];
      p += __shfl_xor(p,1); p += __shfl_xor(p,2);
      p += __shfl_xor(p,4); p += __shfl_xor(p,8);
      if (s == 0){
        float zv = z_s[i0+j][dl];
        y_s[i0+j][dl] = (p + Dd*xv[j]) * (zv / (1.f + __expf(-zv)));
      }
    }
  }
  __syncthreads();
  // coalesced bf16 pack + store: 16 bf16 per row = 2 x 16B
  for (int lin = tid; lin < TC*2; lin += 256){
    int i = lin >> 1, dd8 = (lin & 1)*8;
    bf16x8 v;
#pragma unroll
    for (int k=0;k<8;k++) v[k] = (short)f2bf(y_s[i][dd8+k]);
    *(bf16x8*)&yg[(r0+i)*DI + d0 + dd8] = v;
  }
}

// ---------------- final-row LN (only t = T-1 needed) -> comb half
__global__ __launch_bounds__(64) void k_final(const float* __restrict__ hcur,
    const float* __restrict__ res, const float* __restrict__ nfw, const float* __restrict__ nfb,
    float* __restrict__ comb, int half){
  int b = blockIdx.x;
  int lane = threadIdx.x;
  const float* h = hcur + ((long)b*T + (T-1))*DM;
  const float* r = res  + ((long)b*T + (T-1))*DM;
  float v0 = h[lane]+r[lane], v1 = h[lane+64]+r[lane+64];
  float s = v0+v1;
#pragma unroll
  for (int m=1;m<64;m<<=1) s += __shfl_xor(s, m);
  float mu = s * (1.f/128.f);
  float d0 = v0-mu, d1 = v1-mu;
  float q = d0*d0 + d1*d1;
#pragma unroll
  for (int m=1;m<64;m<<=1) q += __shfl_xor(q, m);
  float rstd = rsqrtf(q*(1.f/128.f) + 1e-5f);
  comb[b*2*DM + half*DM + lane]    = d0*rstd*nfw[lane]    + nfb[lane];
  comb[b*2*DM + half*DM + lane+64] = d1*rstd*nfw[lane+64] + nfb[lane+64];
}

// ---------------- head: out(24,256) = comb(24,256) @ head_w^T + head_b
__global__ __launch_bounds__(256) void k_head(const float* __restrict__ comb,
    const float* __restrict__ hw, const float* __restrict__ hb, float* __restrict__ out){
  int b = blockIdx.x, n = threadIdx.x;
  const float* cr = comb + b*2*DM;
  float acc = hb[n];
#pragma unroll 4
  for (int k=0;k<2*DM;k++) acc = fmaf(cr[k], hw[n*2*DM + k], acc);
  out[b*NC + n] = acc;
}

extern "C" void kernel_launch(void* const* d_in, const int* in_sizes, int n_in,
                              void* d_out, int out_size, void* d_ws, size_t ws_size,
                              hipStream_t stream){
  auto F = [&](int i){ return (const float*)d_in[i]; };
  float* ws = (float*)d_ws;
  size_t o = 0;
  float* h0f = ws + o; o += (size_t)ROWS*DM;
  float* h0b = ws + o; o += (size_t)ROWS*DM;
  float* res = ws + o; o += (size_t)ROWS*DM;
  float* hcur= ws + o; o += (size_t)ROWS*DM;
  float* xz  = ws + o; o += (size_t)ROWS*2*DI;
  float* xc  = ws + o; o += (size_t)ROWS*DI;
  float* gdt = ws + o; o += (size_t)ROWS*DI;
  float* bcg = ws + o; o += (size_t)ROWS*2*DS;
  // bf16 region shared by hn (ROWS*DM) and y (ROWS*DI): lifetimes disjoint
  unsigned short* ybf = (unsigned short*)(ws + o); o += (size_t)ROWS*DI/2;
  unsigned short* hnbf = ybf;
  float* Pd  = ws + o; o += (size_t)Bb*NCH*DI*DS;
  float* Hl  = ws + o; o += (size_t)Bb*NCH*DI*DS;
  float* Hst = ws + o; o += (size_t)Bb*NCH*DI*DS;
  unsigned short* wbf = (unsigned short*)(ws + o); o += (size_t)2*NL*(2*DI*DM + DM*DI)/2;
  float* comb= ws + o; o += (size_t)Bb*2*DM;

  // weight casts: [f_inp][f_outp][b_inp][b_outp]
  const int NI = NL*2*DI*DM;   // 262144
  const int NO = NL*DM*DI;     // 131072
  k_cast<<<(NI+255)/256, 256, 0, stream>>>(F(3),  wbf,            NI);
  k_cast<<<(NO+255)/256, 256, 0, stream>>>(F(11), wbf+NI,         NO);
  k_cast<<<(NI+255)/256, 256, 0, stream>>>(F(14), wbf+NI+NO,      NI);
  k_cast<<<(NO+255)/256, 256, 0, stream>>>(F(22), wbf+2*NI+NO,    NO);

  k_conv0<<<ROWS*DM/256, 256, 0, stream>>>(F(0), F(1), F(2), h0f, h0b);

  for (int dir = 0; dir < 2; dir++){
    int p = dir ? 14 : 3;   // f_* at 3..13, b_* at 14..24
    const float* hin = dir ? h0b : h0f;
    unsigned short* winp  = wbf + (size_t)dir*(NI+NO);
    unsigned short* woutp = winp + NI;
    for (int l = 0; l < NL; l++){
      const float* hsrc = (l==0) ? hin : hcur;
      k_add_ln<<<ROWS/4, 256, 0, stream>>>(hsrc, res,
          F(p+9)+(size_t)l*DM, F(p+10)+(size_t)l*DM, hnbf, (l==0)?1:0);
      k_mgemm<2*DI, DM><<<dim3(ROWS/128, (2*DI)/128), 256, 0, stream>>>(
          hnbf, winp + (size_t)l*2*DI*DM, xz);
      k_convs<<<ROWS*DI/256, 256, 0, stream>>>(xz,
          F(p+1)+(size_t)l*DI*4, F(p+2)+(size_t)l*DI, xc);
      k_dbldt<<<ROWS/16, 256, 0, stream>>>(xc,
          F(p+3)+(size_t)l*(DTR+2*DS)*DI, F(p+4)+(size_t)l*DI*DTR,
          F(p+5)+(size_t)l*DI, gdt, bcg);
      k_scan1<<<dim3(DI/16, NCH, Bb), 256, 0, stream>>>(gdt, bcg, xc,
          F(p+6)+(size_t)l*DI*DS, Pd, Hl);
      k_scan2<<<(Bb*DI*DS)/256, 256, 0, stream>>>(Pd, Hl, Hst);
      k_scan3<<<dim3(DI/16, NCH, Bb), 256, 0, stream>>>(gdt, bcg, xc, xz,
          F(p+6)+(size_t)l*DI*DS, F(p+7)+(size_t)l*DI, Hst, ybf);
      k_mgemm<DM, DI><<<dim3(ROWS/128, DM/128), 256, 0, stream>>>(
          ybf, woutp + (size_t)l*DM*DI, hcur);
    }
    k_final<<<Bb, 64, 0, stream>>>(hcur, res, F(25), F(26), comb, dir);
  }
  k_head<<<Bb, 256, 0, stream>>>(comb, F(27), F(28), (float*)d_out);
}

// Round 7
// 1835.841 us; speedup vs baseline: 2.2058x; 1.3389x over previous
//
#include <hip/hip_runtime.h>
#include <hip/hip_bf16.h>
#include <math.h>

static constexpr int NL=4, DM=128, DI=256, DS=16, DTR=8, NC=256;
static constexpr int Bb=24, Lx=3072, T=1024;
static constexpr int ROWS = Bb*T;       // 24576
static constexpr int NCH=8, TC=128;     // scan chunking

typedef __attribute__((ext_vector_type(4))) float f32x4;
typedef __attribute__((ext_vector_type(8))) short bf16x8;

// f32 -> bf16 (round-to-nearest-even), header-independent
static __device__ inline unsigned short f2bf(float f){
  unsigned int u = __float_as_uint(f);
  unsigned int r = (u + 0x7FFFu + ((u >> 16) & 1u)) >> 16;
  return (unsigned short)r;
}

// DPP-based partial-row add: x += x[lane selected by CTRL]; pure VALU, no DS pipe.
template<int CTRL>
static __device__ __forceinline__ float dpp_add(float x){
  int t = __builtin_amdgcn_update_dpp(0, __float_as_int(x), CTRL, 0xF, 0xF, true);
  return x + __int_as_float(t);
}
// reduce 16-lane row into lane (s==0): quad xor1, quad xor2, row_shr:4, row_shr:8
// (row_shr moves data toward lane 0: lane i reads lane i+N, OOB lanes add 0)
static __device__ __forceinline__ float row16_reduce(float x){
  x = dpp_add<0xB1>(x);    // quad_perm [1,0,3,2]  (xor 1)
  x = dpp_add<0x4E>(x);    // quad_perm [2,3,0,1]  (xor 2)
  x = dpp_add<0x114>(x);   // row_shr:4
  x = dpp_add<0x118>(x);   // row_shr:8
  return x;                // lane 0 of each 16-row holds the full sum
}

// ---------------- initial strided conv: x(B,3072) -> h0 (B,1024,128), plus reversed copy
__global__ __launch_bounds__(256) void k_conv0(const float* __restrict__ x,
    const float* __restrict__ cw, const float* __restrict__ cb,
    float* __restrict__ h0f, float* __restrict__ h0b){
  int idx = blockIdx.x*256 + threadIdx.x;     // B*T*DM total
  int c = idx & (DM-1);
  int t = (idx >> 7) & (T-1);
  int b = idx >> 17;
  const float* xr = x + b*Lx;
  float acc = cb[c];
  int base = 3*t - 1;
#pragma unroll
  for (int k=0;k<3;k++){
    int j = base + k;
    float xv = (j>=0 && j<Lx) ? xr[j] : 0.f;
    acc = fmaf(xv, cw[c*3+k], acc);
  }
  h0f[(b*T + t)*DM + c] = acc;
  h0b[(b*T + (T-1-t))*DM + c] = acc;
}

// ---------------- generic f32 -> bf16 cast
__global__ __launch_bounds__(256) void k_cast(const float* __restrict__ src,
    unsigned short* __restrict__ dst, int n){
  int i = blockIdx.x*256 + threadIdx.x;
  if (i < n) dst[i] = f2bf(src[i]);
}

// ---------------- residual add + LayerNorm over DM=128 -> bf16 hn. 1 wave/row, 4 rows/block
__global__ __launch_bounds__(256) void k_add_ln(const float* __restrict__ hin,
    float* __restrict__ res, const float* __restrict__ lnw, const float* __restrict__ lnb,
    unsigned short* __restrict__ hn, int first){
  int row = blockIdx.x*4 + (threadIdx.x >> 6);
  int lane = threadIdx.x & 63;
  const float* hr = hin + (long)row*DM;
  float* rr = res + (long)row*DM;
  float v0 = hr[lane], v1 = hr[lane+64];
  if (!first){ v0 += rr[lane]; v1 += rr[lane+64]; }
  rr[lane] = v0; rr[lane+64] = v1;
  float s = v0+v1;
#pragma unroll
  for (int m=1;m<64;m<<=1) s += __shfl_xor(s, m);
  float mu = s * (1.f/128.f);
  float d0 = v0-mu, d1 = v1-mu;
  float q = d0*d0 + d1*d1;
#pragma unroll
  for (int m=1;m<64;m<<=1) q += __shfl_xor(q, m);
  float rstd = rsqrtf(q*(1.f/128.f) + 1e-5f);
  hn[(long)row*DM+lane]    = f2bf(d0*rstd*lnw[lane]    + lnb[lane]);
  hn[(long)row*DM+lane+64] = f2bf(d1*rstd*lnw[lane+64] + lnb[lane+64]);
}

// ---------------- bf16 MFMA GEMM: C[M][N](f32) = A[M][K](bf16) * W[N][K](bf16)^T
// tile 128x128, 4 waves (2x2), each wave 64x64 via 4x4 frags of 16x16x32
template<int N, int K>
__global__ __launch_bounds__(256) void k_mgemm(const unsigned short* __restrict__ A,
    const unsigned short* __restrict__ W, float* __restrict__ C){
  constexpr int BK = 32;
  __shared__ short As[128*BK];
  __shared__ short Ws[128*BK];
  int tid = threadIdx.x;
  int lane = tid & 63, wave = tid >> 6;
  int wr = (wave >> 1) * 64, wc = (wave & 1) * 64;
  long bm = blockIdx.x, bn = blockIdx.y;
  const short* Ag = (const short*)A + bm*128*K;
  const short* Wg = (const short*)W + bn*128*K;
  f32x4 acc[4][4] = {};
  int r = lane & 15, kg = (lane >> 4) * 8;
  for (int kb = 0; kb < K; kb += BK){
#pragma unroll
    for (int t = 0; t < 2; t++){
      int c = tid + t*256;            // 512 chunks of 16B per 8KB tile
      int row = c >> 2, kc = (c & 3) * 8;
      *(bf16x8*)&As[row*BK + kc] = *(const bf16x8*)&Ag[row*K + kb + kc];
      *(bf16x8*)&Ws[row*BK + kc] = *(const bf16x8*)&Wg[row*K + kb + kc];
    }
    __syncthreads();
    bf16x8 af[4], wf[4];
#pragma unroll
    for (int m=0;m<4;m++) af[m] = *(const bf16x8*)&As[(wr + m*16 + r)*BK + kg];
#pragma unroll
    for (int n=0;n<4;n++) wf[n] = *(const bf16x8*)&Ws[(wc + n*16 + r)*BK + kg];
#pragma unroll
    for (int m=0;m<4;m++)
#pragma unroll
      for (int n=0;n<4;n++)
        acc[m][n] = __builtin_amdgcn_mfma_f32_16x16x32_bf16(af[m], wf[n], acc[m][n], 0, 0, 0);
    __syncthreads();
  }
  float* Cb = C + (bm*128)*N + bn*128;
  int rq = (lane >> 4) * 4, cn = lane & 15;
#pragma unroll
  for (int m=0;m<4;m++)
#pragma unroll
    for (int n=0;n<4;n++)
#pragma unroll
      for (int q=0;q<4;q++)
        Cb[(wr + m*16 + rq + q)*N + wc + n*16 + cn] = acc[m][n][q];
}

// ---------------- causal depthwise conv (k=4, pad 3 left) + SiLU ; x = xz[...,0:256]
__global__ __launch_bounds__(256) void k_convs(const float* __restrict__ xz,
    const float* __restrict__ cw, const float* __restrict__ cb, float* __restrict__ xc){
  int idx = blockIdx.x*256 + threadIdx.x;     // B*T*DI
  int d = idx & (DI-1);
  int t = (idx >> 8) & (T-1);
  int b = idx >> 18;
  const float* xrow = xz + (long)b*T*2*DI;
  float acc = cb[d];
#pragma unroll
  for (int k=0;k<4;k++){
    int tt = t + k - 3;
    float xv = (tt>=0) ? xrow[(long)tt*2*DI + d] : 0.f;
    acc = fmaf(xv, cw[d*4+k], acc);
  }
  float s = acc / (1.f + __expf(-acc));
  xc[(long)(b*T+t)*DI + d] = s;
}

// ---------------- dbl = xc @ xp^T (40 cols), dt = softplus(dbl[:,:8] @ dtw^T + dtb), BC out
__global__ __launch_bounds__(256) void k_dbldt(const float* __restrict__ xc,
    const float* __restrict__ xp, const float* __restrict__ dtw, const float* __restrict__ dtb,
    float* __restrict__ gdt, float* __restrict__ bcg){
  __shared__ float xp_s[40][257];
  __shared__ float xc_s[16][257];
  __shared__ float dtw_s[DI][9];
  __shared__ float dtb_s[DI];
  __shared__ float dbl_s[16][41];
  int tid = threadIdx.x;
  long row0 = (long)blockIdx.x * 16;
  for (int lin = tid; lin < 40*DI; lin += 256){
    int n = lin >> 8, k = lin & 255;
    xp_s[n][k] = xp[lin];
  }
  for (int lin = tid; lin < DI*DTR; lin += 256)
    dtw_s[lin>>3][lin&7] = dtw[lin];
  dtb_s[tid] = dtb[tid];
  for (int lin = tid; lin < 16*DI; lin += 256){
    int r = lin >> 8, k = lin & 255;
    xc_s[r][k] = xc[(row0 + r)*DI + k];
  }
  __syncthreads();
  for (int idx = tid; idx < 16*40; idx += 256){
    int r = idx / 40, n = idx % 40;
    float acc = 0.f;
#pragma unroll 4
    for (int k=0;k<DI;k++) acc = fmaf(xc_s[r][k], xp_s[n][k], acc);
    dbl_s[r][n] = acc;
  }
  __syncthreads();
  {
    int d = tid;
    float w[8];
#pragma unroll
    for (int j=0;j<8;j++) w[j] = dtw_s[d][j];
    float bias = dtb_s[d];
    for (int r=0;r<16;r++){
      float acc = bias;
#pragma unroll
      for (int j=0;j<8;j++) acc = fmaf(dbl_s[r][j], w[j], acc);
      float sp = (acc > 20.f) ? acc : log1pf(__expf(acc));
      gdt[(row0 + r)*DI + d] = sp;
    }
  }
  for (int idx = tid; idx < 16*32; idx += 256){
    int r = idx >> 5, j = idx & 31;
    bcg[(row0 + r)*32 + j] = dbl_s[r][8 + j];
  }
}

// ---------------- scan pass 1: per-chunk decay product + local final state (h0=0)
// grid (DI/16, NCH, Bb); block 256 = 16 d x 16 s
__global__ __launch_bounds__(256) void k_scan1(const float* __restrict__ gdt,
    const float* __restrict__ bcg, const float* __restrict__ xc,
    const float* __restrict__ Alog, float* __restrict__ Pd, float* __restrict__ Hl){
  int b = blockIdx.z, ch = blockIdx.y, d0 = blockIdx.x*16;
  int tid = threadIdx.x, s = tid & 15, dl = tid >> 4, d = d0 + dl;
  float A = -__expf(Alog[d*DS + s]);
  __shared__ float dt_s[TC][16], x_s[TC][16], b_s[TC][16];
  long r0 = (long)b*T + ch*TC;
  for (int lin = tid; lin < TC*4; lin += 256){
    int i = lin >> 2, c4 = (lin & 3)*4;
    *(float4*)&dt_s[i][c4] = *(const float4*)&gdt[(r0+i)*DI + d0 + c4];
    *(float4*)&x_s[i][c4]  = *(const float4*)&xc [(r0+i)*DI + d0 + c4];
    *(float4*)&b_s[i][c4]  = *(const float4*)&bcg[(r0+i)*32 + c4];
  }
  __syncthreads();
  float h = 0.f, lp = 0.f;
  for (int i0 = 0; i0 < TC; i0 += 8){
    float dtv[8], xv[8], bv[8];
#pragma unroll
    for (int j=0;j<8;j++){ dtv[j]=dt_s[i0+j][dl]; xv[j]=x_s[i0+j][dl]; bv[j]=b_s[i0+j][s]; }
#pragma unroll
    for (int j=0;j<8;j++){
      float da = dtv[j]*A;
      lp += da;
      h = fmaf(__expf(da), h, dtv[j]*xv[j]*bv[j]);
    }
  }
  long o = ((long)(b*NCH + ch)*DI + d)*DS + s;
  Pd[o] = __expf(lp);
  Hl[o] = h;
}

// ---------------- scan pass 2: sequential chunk combine -> per-chunk start states
__global__ __launch_bounds__(256) void k_scan2(const float* __restrict__ Pd,
    const float* __restrict__ Hl, float* __restrict__ Hst){
  int idx = blockIdx.x*256 + threadIdx.x;   // b*4096 + (d*16+s)
  int b = idx >> 12, j = idx & 4095;
  long base = (long)b*NCH*4096 + j;
  float h = 0.f;
#pragma unroll
  for (int c=0;c<NCH;c++){
    Hst[base + c*4096] = h;
    h = Pd[base + c*4096]*h + Hl[base + c*4096];
  }
}

// ---------------- scan pass 3: full local scan with correct h0, emit gated y (bf16)
// grid (DI/16, NCH, Bb); block 256 = 16 d x 16 s
// step reduce over s done with pure-VALU DPP adds (no ds_swizzle latency chain)
__global__ __launch_bounds__(256) void k_scan3(const float* __restrict__ gdt,
    const float* __restrict__ bcg, const float* __restrict__ xc, const float* __restrict__ xz,
    const float* __restrict__ Alog, const float* __restrict__ Dp,
    const float* __restrict__ Hst, unsigned short* __restrict__ yg){
  int b = blockIdx.z, ch = blockIdx.y, d0 = blockIdx.x*16;
  int tid = threadIdx.x, s = tid & 15, dl = tid >> 4, d = d0 + dl;
  float A = -__expf(Alog[d*DS + s]);
  float Dd = Dp[d];
  __shared__ float dt_s[TC][16], x_s[TC][16], z_s[TC][16], b_s[TC][16], c_s[TC][16];
  __shared__ float y_s[TC][16];
  long r0 = (long)b*T + ch*TC;
  for (int lin = tid; lin < TC*4; lin += 256){
    int i = lin >> 2, c4 = (lin & 3)*4;
    *(float4*)&dt_s[i][c4] = *(const float4*)&gdt[(r0+i)*DI + d0 + c4];
    *(float4*)&x_s[i][c4]  = *(const float4*)&xc [(r0+i)*DI + d0 + c4];
    float4 zv = *(const float4*)&xz [(r0+i)*2*DI + DI + d0 + c4];
    zv.x = zv.x/(1.f+__expf(-zv.x)); zv.y = zv.y/(1.f+__expf(-zv.y));
    zv.z = zv.z/(1.f+__expf(-zv.z)); zv.w = zv.w/(1.f+__expf(-zv.w));
    *(float4*)&z_s[i][c4]  = zv;     // z_s holds silu(z)
    *(float4*)&b_s[i][c4]  = *(const float4*)&bcg[(r0+i)*32 + c4];
    *(float4*)&c_s[i][c4]  = *(const float4*)&bcg[(r0+i)*32 + 16 + c4];
  }
  float h = Hst[((long)(b*NCH + ch)*DI + d)*DS + s];
  __syncthreads();
  for (int i0 = 0; i0 < TC; i0 += 8){
    float dtv[8], xv[8], bv[8], cv[8], dec[8], ad[8], p[8];
#pragma unroll
    for (int j=0;j<8;j++){
      dtv[j]=dt_s[i0+j][dl]; xv[j]=x_s[i0+j][dl];
      bv[j]=b_s[i0+j][s];    cv[j]=c_s[i0+j][s];
    }
#pragma unroll
    for (int j=0;j<8;j++){ dec[j] = __expf(dtv[j]*A); ad[j] = dtv[j]*xv[j]*bv[j]; }
#pragma unroll
    for (int j=0;j<8;j++){ h = fmaf(dec[j], h, ad[j]); p[j] = h * cv[j]; }
    // 4-stage DPP reduce (toward lane 0), 8 independent chains per stage (pipelines)
#pragma unroll
    for (int j=0;j<8;j++) p[j] = dpp_add<0xB1>(p[j]);
#pragma unroll
    for (int j=0;j<8;j++) p[j] = dpp_add<0x4E>(p[j]);
#pragma unroll
    for (int j=0;j<8;j++) p[j] = dpp_add<0x114>(p[j]);
#pragma unroll
    for (int j=0;j<8;j++) p[j] = dpp_add<0x118>(p[j]);
    if (s == 0){
#pragma unroll
      for (int j=0;j<8;j++)
        y_s[i0+j][dl] = fmaf(Dd, xv[j], p[j]) * z_s[i0+j][dl];
    }
  }
  __syncthreads();
  // coalesced bf16 pack + store: 16 bf16 per row = 2 x 16B
  for (int lin = tid; lin < TC*2; lin += 256){
    int i = lin >> 1, dd8 = (lin & 1)*8;
    bf16x8 v;
#pragma unroll
    for (int k=0;k<8;k++) v[k] = (short)f2bf(y_s[i][dd8+k]);
    *(bf16x8*)&yg[(r0+i)*DI + d0 + dd8] = v;
  }
}

// ---------------- final-row LN (only t = T-1 needed) -> comb half
__global__ __launch_bounds__(64) void k_final(const float* __restrict__ hcur,
    const float* __restrict__ res, const float* __restrict__ nfw, const float* __restrict__ nfb,
    float* __restrict__ comb, int half){
  int b = blockIdx.x;
  int lane = threadIdx.x;
  const float* h = hcur + ((long)b*T + (T-1))*DM;
  const float* r = res  + ((long)b*T + (T-1))*DM;
  float v0 = h[lane]+r[lane], v1 = h[lane+64]+r[lane+64];
  float s = v0+v1;
#pragma unroll
  for (int m=1;m<64;m<<=1) s += __shfl_xor(s, m);
  float mu = s * (1.f/128.f);
  float d0 = v0-mu, d1 = v1-mu;
  float q = d0*d0 + d1*d1;
#pragma unroll
  for (int m=1;m<64;m<<=1) q += __shfl_xor(q, m);
  float rstd = rsqrtf(q*(1.f/128.f) + 1e-5f);
  comb[b*2*DM + half*DM + lane]    = d0*rstd*nfw[lane]    + nfb[lane];
  comb[b*2*DM + half*DM + lane+64] = d1*rstd*nfw[lane+64] + nfb[lane+64];
}

// ---------------- head: out(24,256) = comb(24,256) @ head_w^T + head_b
__global__ __launch_bounds__(256) void k_head(const float* __restrict__ comb,
    const float* __restrict__ hw, const float* __restrict__ hb, float* __restrict__ out){
  int b = blockIdx.x, n = threadIdx.x;
  const float* cr = comb + b*2*DM;
  float acc = hb[n];
#pragma unroll 4
  for (int k=0;k<2*DM;k++) acc = fmaf(cr[k], hw[n*2*DM + k], acc);
  out[b*NC + n] = acc;
}

extern "C" void kernel_launch(void* const* d_in, const int* in_sizes, int n_in,
                              void* d_out, int out_size, void* d_ws, size_t ws_size,
                              hipStream_t stream){
  auto F = [&](int i){ return (const float*)d_in[i]; };
  float* ws = (float*)d_ws;
  size_t o = 0;
  float* h0f = ws + o; o += (size_t)ROWS*DM;
  float* h0b = ws + o; o += (size_t)ROWS*DM;
  float* res = ws + o; o += (size_t)ROWS*DM;
  float* hcur= ws + o; o += (size_t)ROWS*DM;
  float* xz  = ws + o; o += (size_t)ROWS*2*DI;
  float* xc  = ws + o; o += (size_t)ROWS*DI;
  float* gdt = ws + o; o += (size_t)ROWS*DI;
  float* bcg = ws + o; o += (size_t)ROWS*2*DS;
  // bf16 region shared by hn (ROWS*DM) and y (ROWS*DI): lifetimes disjoint
  unsigned short* ybf = (unsigned short*)(ws + o); o += (size_t)ROWS*DI/2;
  unsigned short* hnbf = ybf;
  float* Pd  = ws + o; o += (size_t)Bb*NCH*DI*DS;
  float* Hl  = ws + o; o += (size_t)Bb*NCH*DI*DS;
  float* Hst = ws + o; o += (size_t)Bb*NCH*DI*DS;
  unsigned short* wbf = (unsigned short*)(ws + o); o += (size_t)2*NL*(2*DI*DM + DM*DI)/2;
  float* comb= ws + o; o += (size_t)Bb*2*DM;

  // weight casts: [f_inp][f_outp][b_inp][b_outp]
  const int NI = NL*2*DI*DM;   // 262144
  const int NO = NL*DM*DI;     // 131072
  k_cast<<<(NI+255)/256, 256, 0, stream>>>(F(3),  wbf,            NI);
  k_cast<<<(NO+255)/256, 256, 0, stream>>>(F(11), wbf+NI,         NO);
  k_cast<<<(NI+255)/256, 256, 0, stream>>>(F(14), wbf+NI+NO,      NI);
  k_cast<<<(NO+255)/256, 256, 0, stream>>>(F(22), wbf+2*NI+NO,    NO);

  k_conv0<<<ROWS*DM/256, 256, 0, stream>>>(F(0), F(1), F(2), h0f, h0b);

  for (int dir = 0; dir < 2; dir++){
    int p = dir ? 14 : 3;   // f_* at 3..13, b_* at 14..24
    const float* hin = dir ? h0b : h0f;
    unsigned short* winp  = wbf + (size_t)dir*(NI+NO);
    unsigned short* woutp = winp + NI;
    for (int l = 0; l < NL; l++){
      const float* hsrc = (l==0) ? hin : hcur;
      k_add_ln<<<ROWS/4, 256, 0, stream>>>(hsrc, res,
          F(p+9)+(size_t)l*DM, F(p+10)+(size_t)l*DM, hnbf, (l==0)?1:0);
      k_mgemm<2*DI, DM><<<dim3(ROWS/128, (2*DI)/128), 256, 0, stream>>>(
          hnbf, winp + (size_t)l*2*DI*DM, xz);
      k_convs<<<ROWS*DI/256, 256, 0, stream>>>(xz,
          F(p+1)+(size_t)l*DI*4, F(p+2)+(size_t)l*DI, xc);
      k_dbldt<<<ROWS/16, 256, 0, stream>>>(xc,
          F(p+3)+(size_t)l*(DTR+2*DS)*DI, F(p+4)+(size_t)l*DI*DTR,
          F(p+5)+(size_t)l*DI, gdt, bcg);
      k_scan1<<<dim3(DI/16, NCH, Bb), 256, 0, stream>>>(gdt, bcg, xc,
          F(p+6)+(size_t)l*DI*DS, Pd, Hl);
      k_scan2<<<(Bb*DI*DS)/256, 256, 0, stream>>>(Pd, Hl, Hst);
      k_scan3<<<dim3(DI/16, NCH, Bb), 256, 0, stream>>>(gdt, bcg, xc, xz,
          F(p+6)+(size_t)l*DI*DS, F(p+7)+(size_t)l*DI, Hst, ybf);
      k_mgemm<DM, DI><<<dim3(ROWS/128, DM/128), 256, 0, stream>>>(
          ybf, woutp + (size_t)l*DM*DI, hcur);
    }
    k_final<<<Bb, 64, 0, stream>>>(hcur, res, F(25), F(26), comb, dir);
  }
  k_head<<<Bb, 256, 0, stream>>>(comb, F(27), F(28), (float*)d_out);
}

// Round 9
// 1577.744 us; speedup vs baseline: 2.5666x; 1.1636x over previous
//
#include <hip/hip_runtime.h>
#include <hip/hip_bf16.h>
#include <math.h>

static constexpr int NL=4, DM=128, DI=256, DS=16, DTR=8, NC=256;
static constexpr int Bb=24, Lx=3072, T=1024;
static constexpr int ROWS = Bb*T;       // 24576
static constexpr int NCH=8, TC=128;     // scan chunking

typedef __attribute__((ext_vector_type(4))) float f32x4;
typedef __attribute__((ext_vector_type(8))) short bf16x8;

// f32 -> bf16 (round-to-nearest-even), header-independent
static __device__ inline unsigned short f2bf(float f){
  unsigned int u = __float_as_uint(f);
  unsigned int r = (u + 0x7FFFu + ((u >> 16) & 1u)) >> 16;
  return (unsigned short)r;
}

// DPP-based partial-row add: x += x[lane selected by CTRL]; pure VALU, no DS pipe.
template<int CTRL>
static __device__ __forceinline__ float dpp_add(float x){
  int t = __builtin_amdgcn_update_dpp(0, __float_as_int(x), CTRL, 0xF, 0xF, true);
  return x + __int_as_float(t);
}

// ---------------- initial strided conv: x(B,3072) -> h0 (B,1024,128), plus reversed copy
__global__ __launch_bounds__(256) void k_conv0(const float* __restrict__ x,
    const float* __restrict__ cw, const float* __restrict__ cb,
    float* __restrict__ h0f, float* __restrict__ h0b){
  int idx = blockIdx.x*256 + threadIdx.x;     // B*T*DM total
  int c = idx & (DM-1);
  int t = (idx >> 7) & (T-1);
  int b = idx >> 17;
  const float* xr = x + b*Lx;
  float acc = cb[c];
  int base = 3*t - 1;
#pragma unroll
  for (int k=0;k<3;k++){
    int j = base + k;
    float xv = (j>=0 && j<Lx) ? xr[j] : 0.f;
    acc = fmaf(xv, cw[c*3+k], acc);
  }
  h0f[(b*T + t)*DM + c] = acc;
  h0b[(b*T + (T-1-t))*DM + c] = acc;
}

// ---------------- generic f32 -> bf16 cast
__global__ __launch_bounds__(256) void k_cast(const float* __restrict__ src,
    unsigned short* __restrict__ dst, int n){
  int i = blockIdx.x*256 + threadIdx.x;
  if (i < n) dst[i] = f2bf(src[i]);
}

// ---------------- residual add + LayerNorm over DM=128 -> bf16 hn. 1 wave/row, 4 rows/block
__global__ __launch_bounds__(256) void k_add_ln(const float* __restrict__ hin,
    float* __restrict__ res, const float* __restrict__ lnw, const float* __restrict__ lnb,
    unsigned short* __restrict__ hn, int first){
  int row = blockIdx.x*4 + (threadIdx.x >> 6);
  int lane = threadIdx.x & 63;
  const float* hr = hin + (long)row*DM;
  float* rr = res + (long)row*DM;
  float v0 = hr[lane], v1 = hr[lane+64];
  if (!first){ v0 += rr[lane]; v1 += rr[lane+64]; }
  rr[lane] = v0; rr[lane+64] = v1;
  float s = v0+v1;
#pragma unroll
  for (int m=1;m<64;m<<=1) s += __shfl_xor(s, m);
  float mu = s * (1.f/128.f);
  float d0 = v0-mu, d1 = v1-mu;
  float q = d0*d0 + d1*d1;
#pragma unroll
  for (int m=1;m<64;m<<=1) q += __shfl_xor(q, m);
  float rstd = rsqrtf(q*(1.f/128.f) + 1e-5f);
  hn[(long)row*DM+lane]    = f2bf(d0*rstd*lnw[lane]    + lnb[lane]);
  hn[(long)row*DM+lane+64] = f2bf(d1*rstd*lnw[lane+64] + lnb[lane+64]);
}

// ---------------- bf16 MFMA GEMM: C[M][N](f32) = A[M][K](bf16) * W[N][K](bf16)^T
// tile 128x128, 4 waves (2x2), each wave 64x64 via 4x4 frags of 16x16x32
template<int N, int K>
__global__ __launch_bounds__(256) void k_mgemm(const unsigned short* __restrict__ A,
    const unsigned short* __restrict__ W, float* __restrict__ C){
  constexpr int BK = 32;
  __shared__ short As[128*BK];
  __shared__ short Ws[128*BK];
  int tid = threadIdx.x;
  int lane = tid & 63, wave = tid >> 6;
  int wr = (wave >> 1) * 64, wc = (wave & 1) * 64;
  long bm = blockIdx.x, bn = blockIdx.y;
  const short* Ag = (const short*)A + bm*128*K;
  const short* Wg = (const short*)W + bn*128*K;
  f32x4 acc[4][4] = {};
  int r = lane & 15, kg = (lane >> 4) * 8;
  for (int kb = 0; kb < K; kb += BK){
#pragma unroll
    for (int t = 0; t < 2; t++){
      int c = tid + t*256;            // 512 chunks of 16B per 8KB tile
      int row = c >> 2, kc = (c & 3) * 8;
      *(bf16x8*)&As[row*BK + kc] = *(const bf16x8*)&Ag[row*K + kb + kc];
      *(bf16x8*)&Ws[row*BK + kc] = *(const bf16x8*)&Wg[row*K + kb + kc];
    }
    __syncthreads();
    bf16x8 af[4], wf[4];
#pragma unroll
    for (int m=0;m<4;m++) af[m] = *(const bf16x8*)&As[(wr + m*16 + r)*BK + kg];
#pragma unroll
    for (int n=0;n<4;n++) wf[n] = *(const bf16x8*)&Ws[(wc + n*16 + r)*BK + kg];
#pragma unroll
    for (int m=0;m<4;m++)
#pragma unroll
      for (int n=0;n<4;n++)
        acc[m][n] = __builtin_amdgcn_mfma_f32_16x16x32_bf16(af[m], wf[n], acc[m][n], 0, 0, 0);
    __syncthreads();
  }
  float* Cb = C + (bm*128)*N + bn*128;
  int rq = (lane >> 4) * 4, cn = lane & 15;
#pragma unroll
  for (int m=0;m<4;m++)
#pragma unroll
    for (int n=0;n<4;n++)
#pragma unroll
      for (int q=0;q<4;q++)
        Cb[(wr + m*16 + rq + q)*N + wc + n*16 + cn] = acc[m][n][q];
}

// ---------------- causal depthwise conv (k=4, pad 3 left) + SiLU ; x = xz[...,0:256]
// writes f32 xc (for scans) and bf16 xcb (for dbl MFMA)
__global__ __launch_bounds__(256) void k_convs(const float* __restrict__ xz,
    const float* __restrict__ cw, const float* __restrict__ cb,
    float* __restrict__ xc, unsigned short* __restrict__ xcb){
  int idx = blockIdx.x*256 + threadIdx.x;     // B*T*DI
  int d = idx & (DI-1);
  int t = (idx >> 8) & (T-1);
  int b = idx >> 18;
  const float* xrow = xz + (long)b*T*2*DI;
  float acc = cb[d];
#pragma unroll
  for (int k=0;k<4;k++){
    int tt = t + k - 3;
    float xv = (tt>=0) ? xrow[(long)tt*2*DI + d] : 0.f;
    acc = fmaf(xv, cw[d*4+k], acc);
  }
  float s = acc / (1.f + __expf(-acc));
  long o = (long)(b*T+t)*DI + d;
  xc[o] = s;
  xcb[o] = f2bf(s);
}

// ---------------- dbl = xc @ xp^T (40 cols) via MFMA; dt = softplus(dbl[:,:8]@dtw^T+dtb)
// block = 64 rows, 256 threads (4 waves x 16 rows); A-frags straight from global,
// xp staged in LDS (pad to 264 shorts -> only free 2-way bank aliasing)
__global__ __launch_bounds__(256) void k_dbldt(const unsigned short* __restrict__ xcb,
    const unsigned short* __restrict__ xpb, const float* __restrict__ dtw,
    const float* __restrict__ dtb, float* __restrict__ gdt, float* __restrict__ bcg){
  constexpr int BP = 264;                    // padded row stride (shorts)
  __shared__ short B_s[48*BP];               // 25344 B
  __shared__ float dbl_s[64][9];             // 2304 B
  __shared__ float bc_s[64][33];             // 8448 B
  int tid = threadIdx.x;
  int lane = tid & 63, wave = tid >> 6;
  int wr = wave * 16;                        // wave's row group
  long row0 = (long)blockIdx.x * 64;
  // per-thread dt weights (coalesced-ish 32B/thread, L2-hot after first block)
  float w[8];
#pragma unroll
  for (int j=0;j<8;j++) w[j] = dtw[tid*8 + j];
  float bias = dtb[tid];
  // stage xp (40 rows) + zero pad rows 40..47
  for (int c = tid; c < 48*32; c += 256){
    int rowp = c >> 5, k8 = (c & 31) * 8;
    bf16x8 v = {};
    if (rowp < 40) v = *(const bf16x8*)&xpb[rowp*256 + k8];
    *(bf16x8*)&B_s[rowp*BP + k8] = v;
  }
  __syncthreads();
  int cf = lane & 15, hi = lane >> 4;
  const short* Ag = (const short*)xcb + (row0 + wr + cf)*DI + hi*8;
  f32x4 acc[3] = {};
#pragma unroll
  for (int ks = 0; ks < 8; ks++){
    bf16x8 af = *(const bf16x8*)&Ag[ks*32];
#pragma unroll
    for (int n = 0; n < 3; n++){
      bf16x8 bf = *(const bf16x8*)&B_s[(n*16 + cf)*BP + ks*32 + hi*8];
      acc[n] = __builtin_amdgcn_mfma_f32_16x16x32_bf16(af, bf, acc[n], 0, 0, 0);
    }
  }
  // epilogue scatter: col<8 -> dbl_s, 8..39 -> bc_s, >=40 discard
#pragma unroll
  for (int n = 0; n < 3; n++){
    int col = n*16 + cf;
#pragma unroll
    for (int q = 0; q < 4; q++){
      int row = wr + hi*4 + q;
      float v = acc[n][q];
      if (col < 8)       dbl_s[row][col]    = v;
      else if (col < 40) bc_s[row][col - 8] = v;
    }
  }
  __syncthreads();
  // coalesced B/C store: 64 rows x 32 cols
#pragma unroll
  for (int i = 0; i < 8; i++){
    int idx = tid + i*256;
    int row = idx >> 5, col = idx & 31;
    bcg[(row0 + row)*32 + col] = bc_s[row][col];
  }
  // dt: thread owns channel d=tid; dbl_s reads broadcast (conflict-free)
  for (int r = 0; r < 64; r++){
    float a = bias;
#pragma unroll
    for (int j = 0; j < 8; j++) a = fmaf(dbl_s[r][j], w[j], a);
    float sp = (a > 20.f) ? a : log1pf(__expf(a));
    gdt[(row0 + r)*DI + tid] = sp;
  }
}

// ---------------- scan pass 1: per-chunk decay product + local final state (h0=0)
// grid (DI/16, NCH, Bb); block 256 = 16 d x 16 s
__global__ __launch_bounds__(256) void k_scan1(const float* __restrict__ gdt,
    const float* __restrict__ bcg, const float* __restrict__ xc,
    const float* __restrict__ Alog, float* __restrict__ Pd, float* __restrict__ Hl){
  int b = blockIdx.z, ch = blockIdx.y, d0 = blockIdx.x*16;
  int tid = threadIdx.x, s = tid & 15, dl = tid >> 4, d = d0 + dl;
  float A = -__expf(Alog[d*DS + s]);
  __shared__ float dt_s[TC][16], x_s[TC][16], b_s[TC][16];
  long r0 = (long)b*T + ch*TC;
  for (int lin = tid; lin < TC*4; lin += 256){
    int i = lin >> 2, c4 = (lin & 3)*4;
    *(float4*)&dt_s[i][c4] = *(const float4*)&gdt[(r0+i)*DI + d0 + c4];
    *(float4*)&x_s[i][c4]  = *(const float4*)&xc [(r0+i)*DI + d0 + c4];
    *(float4*)&b_s[i][c4]  = *(const float4*)&bcg[(r0+i)*32 + c4];
  }
  __syncthreads();
  float h = 0.f, lp = 0.f;
  for (int i0 = 0; i0 < TC; i0 += 8){
    float dtv[8], xv[8], bv[8];
#pragma unroll
    for (int j=0;j<8;j++){ dtv[j]=dt_s[i0+j][dl]; xv[j]=x_s[i0+j][dl]; bv[j]=b_s[i0+j][s]; }
#pragma unroll
    for (int j=0;j<8;j++){
      float da = dtv[j]*A;
      lp += da;
      h = fmaf(__expf(da), h, dtv[j]*xv[j]*bv[j]);
    }
  }
  long o = ((long)(b*NCH + ch)*DI + d)*DS + s;
  Pd[o] = __expf(lp);
  Hl[o] = h;
}

// ---------------- scan pass 2: sequential chunk combine -> per-chunk start states
__global__ __launch_bounds__(256) void k_scan2(const float* __restrict__ Pd,
    const float* __restrict__ Hl, float* __restrict__ Hst){
  int idx = blockIdx.x*256 + threadIdx.x;   // b*4096 + (d*16+s)
  int b = idx >> 12, j = idx & 4095;
  long base = (long)b*NCH*4096 + j;
  float h = 0.f;
#pragma unroll
  for (int c=0;c<NCH;c++){
    Hst[base + c*4096] = h;
    h = Pd[base + c*4096]*h + Hl[base + c*4096];
  }
}

// ---------------- scan pass 3: full local scan with correct h0, emit gated y (bf16)
// grid (DI/16, NCH, Bb); block 256 = 16 d x 16 s
// step reduce over s done with pure-VALU DPP adds (no ds_swizzle latency chain)
__global__ __launch_bounds__(256) void k_scan3(const float* __restrict__ gdt,
    const float* __restrict__ bcg, const float* __restrict__ xc, const float* __restrict__ xz,
    const float* __restrict__ Alog, const float* __restrict__ Dp,
    const float* __restrict__ Hst, unsigned short* __restrict__ yg){
  int b = blockIdx.z, ch = blockIdx.y, d0 = blockIdx.x*16;
  int tid = threadIdx.x, s = tid & 15, dl = tid >> 4, d = d0 + dl;
  float A = -__expf(Alog[d*DS + s]);
  float Dd = Dp[d];
  __shared__ float dt_s[TC][16], x_s[TC][16], z_s[TC][16], b_s[TC][16], c_s[TC][16];
  __shared__ float y_s[TC][16];
  long r0 = (long)b*T + ch*TC;
  for (int lin = tid; lin < TC*4; lin += 256){
    int i = lin >> 2, c4 = (lin & 3)*4;
    *(float4*)&dt_s[i][c4] = *(const float4*)&gdt[(r0+i)*DI + d0 + c4];
    *(float4*)&x_s[i][c4]  = *(const float4*)&xc [(r0+i)*DI + d0 + c4];
    float4 zv = *(const float4*)&xz [(r0+i)*2*DI + DI + d0 + c4];
    zv.x = zv.x/(1.f+__expf(-zv.x)); zv.y = zv.y/(1.f+__expf(-zv.y));
    zv.z = zv.z/(1.f+__expf(-zv.z)); zv.w = zv.w/(1.f+__expf(-zv.w));
    *(float4*)&z_s[i][c4]  = zv;     // z_s holds silu(z)
    *(float4*)&b_s[i][c4]  = *(const float4*)&bcg[(r0+i)*32 + c4];
    *(float4*)&c_s[i][c4]  = *(const float4*)&bcg[(r0+i)*32 + 16 + c4];
  }
  float h = Hst[((long)(b*NCH + ch)*DI + d)*DS + s];
  __syncthreads();
  for (int i0 = 0; i0 < TC; i0 += 8){
    float dtv[8], xv[8], bv[8], cv[8], dec[8], ad[8], p[8];
#pragma unroll
    for (int j=0;j<8;j++){
      dtv[j]=dt_s[i0+j][dl]; xv[j]=x_s[i0+j][dl];
      bv[j]=b_s[i0+j][s];    cv[j]=c_s[i0+j][s];
    }
#pragma unroll
    for (int j=0;j<8;j++){ dec[j] = __expf(dtv[j]*A); ad[j] = dtv[j]*xv[j]*bv[j]; }
#pragma unroll
    for (int j=0;j<8;j++){ h = fmaf(dec[j], h, ad[j]); p[j] = h * cv[j]; }
    // 4-stage DPP reduce (toward lane 0), 8 independent chains per stage (pipelines)
#pragma unroll
    for (int j=0;j<8;j++) p[j] = dpp_add<0xB1>(p[j]);
#pragma unroll
    for (int j=0;j<8;j++) p[j] = dpp_add<0x4E>(p[j]);
#pragma unroll
    for (int j=0;j<8;j++) p[j] = dpp_add<0x114>(p[j]);
#pragma unroll
    for (int j=0;j<8;j++) p[j] = dpp_add<0x118>(p[j]);
    if (s == 0){
#pragma unroll
      for (int j=0;j<8;j++)
        y_s[i0+j][dl] = fmaf(Dd, xv[j], p[j]) * z_s[i0+j][dl];
    }
  }
  __syncthreads();
  // coalesced bf16 pack + store: 16 bf16 per row = 2 x 16B
  for (int lin = tid; lin < TC*2; lin += 256){
    int i = lin >> 1, dd8 = (lin & 1)*8;
    bf16x8 v;
#pragma unroll
    for (int k=0;k<8;k++) v[k] = (short)f2bf(y_s[i][dd8+k]);
    *(bf16x8*)&yg[(r0+i)*DI + d0 + dd8] = v;
  }
}

// ---------------- final-row LN (only t = T-1 needed) -> comb half
__global__ __launch_bounds__(64) void k_final(const float* __restrict__ hcur,
    const float* __restrict__ res, const float* __restrict__ nfw, const float* __restrict__ nfb,
    float* __restrict__ comb, int half){
  int b = blockIdx.x;
  int lane = threadIdx.x;
  const float* h = hcur + ((long)b*T + (T-1))*DM;
  const float* r = res  + ((long)b*T + (T-1))*DM;
  float v0 = h[lane]+r[lane], v1 = h[lane+64]+r[lane+64];
  float s = v0+v1;
#pragma unroll
  for (int m=1;m<64;m<<=1) s += __shfl_xor(s, m);
  float mu = s * (1.f/128.f);
  float d0 = v0-mu, d1 = v1-mu;
  float q = d0*d0 + d1*d1;
#pragma unroll
  for (int m=1;m<64;m<<=1) q += __shfl_xor(q, m);
  float rstd = rsqrtf(q*(1.f/128.f) + 1e-5f);
  comb[b*2*DM + half*DM + lane]    = d0*rstd*nfw[lane]    + nfb[lane];
  comb[b*2*DM + half*DM + lane+64] = d1*rstd*nfw[lane+64] + nfb[lane+64];
}

// ---------------- head: out(24,256) = comb(24,256) @ head_w^T + head_b
__global__ __launch_bounds__(256) void k_head(const float* __restrict__ comb,
    const float* __restrict__ hw, const float* __restrict__ hb, float* __restrict__ out){
  int b = blockIdx.x, n = threadIdx.x;
  const float* cr = comb + b*2*DM;
  float acc = hb[n];
#pragma unroll 4
  for (int k=0;k<2*DM;k++) acc = fmaf(cr[k], hw[n*2*DM + k], acc);
  out[b*NC + n] = acc;
}

extern "C" void kernel_launch(void* const* d_in, const int* in_sizes, int n_in,
                              void* d_out, int out_size, void* d_ws, size_t ws_size,
                              hipStream_t stream){
  auto F = [&](int i){ return (const float*)d_in[i]; };
  float* ws = (float*)d_ws;
  size_t o = 0;
  float* h0f = ws + o; o += (size_t)ROWS*DM;
  float* h0b = ws + o; o += (size_t)ROWS*DM;
  float* res = ws + o; o += (size_t)ROWS*DM;
  float* hcur= ws + o; o += (size_t)ROWS*DM;
  float* xz  = ws + o; o += (size_t)ROWS*2*DI;
  float* xc  = ws + o; o += (size_t)ROWS*DI;
  float* gdt = ws + o; o += (size_t)ROWS*DI;
  float* bcg = ws + o; o += (size_t)ROWS*2*DS;
  // bf16 region shared by hn (ROWS*DM), xcb (ROWS*DI), y (ROWS*DI):
  // per-layer lifetimes disjoint: hn -> xz-gemm; xcb: convs -> dbldt; y: scan3 -> out-gemm
  unsigned short* ybf = (unsigned short*)(ws + o); o += (size_t)ROWS*DI/2;
  unsigned short* hnbf = ybf;
  unsigned short* xcb  = ybf;
  float* Pd  = ws + o; o += (size_t)Bb*NCH*DI*DS;
  float* Hl  = ws + o; o += (size_t)Bb*NCH*DI*DS;
  float* Hst = ws + o; o += (size_t)Bb*NCH*DI*DS;
  unsigned short* wbf = (unsigned short*)(ws + o); o += (size_t)2*NL*(2*DI*DM + DM*DI)/2;
  unsigned short* xpb = (unsigned short*)(ws + o); o += (size_t)2*NL*40*DI/2;
  float* comb= ws + o; o += (size_t)Bb*2*DM;

  // weight casts: [f_inp][f_outp][b_inp][b_outp] + xp (both dirs)
  const int NI = NL*2*DI*DM;   // 262144
  const int NO = NL*DM*DI;     // 131072
  const int NX = NL*40*DI;     // 40960
  k_cast<<<(NI+255)/256, 256, 0, stream>>>(F(3),  wbf,            NI);
  k_cast<<<(NO+255)/256, 256, 0, stream>>>(F(11), wbf+NI,         NO);
  k_cast<<<(NI+255)/256, 256, 0, stream>>>(F(14), wbf+NI+NO,      NI);
  k_cast<<<(NO+255)/256, 256, 0, stream>>>(F(22), wbf+2*NI+NO,    NO);
  k_cast<<<(NX+255)/256, 256, 0, stream>>>(F(6),  xpb,            NX);
  k_cast<<<(NX+255)/256, 256, 0, stream>>>(F(17), xpb+NX,         NX);

  k_conv0<<<ROWS*DM/256, 256, 0, stream>>>(F(0), F(1), F(2), h0f, h0b);

  for (int dir = 0; dir < 2; dir++){
    int p = dir ? 14 : 3;   // f_* at 3..13, b_* at 14..24
    const float* hin = dir ? h0b : h0f;
    unsigned short* winp  = wbf + (size_t)dir*(NI+NO);
    unsigned short* woutp = winp + NI;
    for (int l = 0; l < NL; l++){
      const float* hsrc = (l==0) ? hin : hcur;
      k_add_ln<<<ROWS/4, 256, 0, stream>>>(hsrc, res,
          F(p+9)+(size_t)l*DM, F(p+10)+(size_t)l*DM, hnbf, (l==0)?1:0);
      k_mgemm<2*DI, DM><<<dim3(ROWS/128, (2*DI)/128), 256, 0, stream>>>(
          hnbf, winp + (size_t)l*2*DI*DM, xz);
      k_convs<<<ROWS*DI/256, 256, 0, stream>>>(xz,
          F(p+1)+(size_t)l*DI*4, F(p+2)+(size_t)l*DI, xc, xcb);
      k_dbldt<<<ROWS/64, 256, 0, stream>>>(xcb,
          xpb + (size_t)(dir*NL + l)*40*DI,
          F(p+4)+(size_t)l*DI*DTR, F(p+5)+(size_t)l*DI, gdt, bcg);
      k_scan1<<<dim3(DI/16, NCH, Bb), 256, 0, stream>>>(gdt, bcg, xc,
          F(p+6)+(size_t)l*DI*DS, Pd, Hl);
      k_scan2<<<(Bb*DI*DS)/256, 256, 0, stream>>>(Pd, Hl, Hst);
      k_scan3<<<dim3(DI/16, NCH, Bb), 256, 0, stream>>>(gdt, bcg, xc, xz,
          F(p+6)+(size_t)l*DI*DS, F(p+7)+(size_t)l*DI, Hst, ybf);
      k_mgemm<DM, DI><<<dim3(ROWS/128, DM/128), 256, 0, stream>>>(
          ybf, woutp + (size_t)l*DM*DI, hcur);
    }
    k_final<<<Bb, 64, 0, stream>>>(hcur, res, F(25), F(26), comb, dir);
  }
  k_head<<<Bb, 256, 0, stream>>>(comb, F(27), F(28), (float*)d_out);
}